// Round 15
// baseline (1091.875 us; speedup 1.0000x reference)
//
#include <hip/hip_runtime.h>
#include <hip/hip_bf16.h>

typedef __attribute__((ext_vector_type(4))) float f32x4;
typedef __attribute__((ext_vector_type(8))) short bf16x8;
typedef __attribute__((ext_vector_type(4))) short s16x4;

#define LCOUNT 6

static __device__ __forceinline__ unsigned short f2b(float f){
  __hip_bfloat16 h = __float2bfloat16(f);
  return __builtin_bit_cast(unsigned short, h);
}
static __device__ __forceinline__ float b2f(unsigned short u){
  unsigned int x = ((unsigned int)u) << 16;
  return __builtin_bit_cast(float, x);
}
static __device__ __forceinline__ void gl16(const void* g, void* l){
  __builtin_amdgcn_global_load_lds(
      (const __attribute__((address_space(1))) void*)g,
      (__attribute__((address_space(3))) void*)l, 16, 0, 0);
}
static __device__ __forceinline__ f32x4 mfma16(bf16x8 a, bf16x8 b, f32x4 c){
  return __builtin_amdgcn_mfma_f32_16x16x32_bf16(a, b, c, 0, 0, 0);
}

// ---------------- setup kernels ----------------
__global__ void k_cvt5(const float* __restrict__ Wq, const float* __restrict__ Wk,
                       const float* __restrict__ Wv, const float* __restrict__ W1,
                       const float* __restrict__ W2,
                       unsigned short* __restrict__ wqb, unsigned short* __restrict__ wkb,
                       unsigned short* __restrict__ wvb, unsigned short* __restrict__ w1b,
                       unsigned short* __restrict__ w2b){
  int i = blockIdx.x*256 + threadIdx.x;
  if (i < 98304) wqb[i] = f2b(Wq[i]);
  else if (i < 196608) wkb[i-98304] = f2b(Wk[i-98304]);
  else if (i < 294912) wvb[i-196608] = f2b(Wv[i-196608]);
  else if (i < 688128) w1b[i-294912] = f2b(W1[i-294912]);
  else w2b[i-688128] = f2b(W2[i-688128]);
}

__global__ void k_cvtdist(const float* __restrict__ dist, unsigned short* __restrict__ db){
  int t = blockIdx.x*256 + threadIdx.x;
  int row = t >> 7, ch = t & 127;
  bf16x8 w;
  if (ch >= 125){
#pragma unroll
    for (int e=0;e<8;e++) w[e] = 0;
  } else {
    const float* p = dist + (size_t)row*1000 + ch*8;
    f32x4 a = *(const f32x4*)p;
    f32x4 b = *(const f32x4*)(p + 4);
#pragma unroll
    for (int e=0;e<4;e++){ w[e] = (short)f2b(a[e]); w[4+e] = (short)f2b(b[e]); }
  }
  *(bf16x8*)&db[(size_t)row*1024 + ch*8] = w;
}

__global__ void k_embed(const float* __restrict__ data, const float* __restrict__ We,
                        const float* __restrict__ be, float* __restrict__ x,
                        unsigned short* __restrict__ xb){
  int idx = blockIdx.x*256 + threadIdx.x;
  int d = idx & 127, bn = idx >> 7;
  float v = data[bn*2]*We[d*2] + data[bn*2+1]*We[d*2+1] + be[d];
  x[idx] = v; xb[idx] = f2b(v);
}

// ---------------- norm-scale reduce: part -> na,nc [32][128] ----------------
__global__ void k_scale(const float* __restrict__ part, int cnt,
                        const float* __restrict__ g, const float* __restrict__ beta,
                        float* __restrict__ na, float* __restrict__ nc){
  int b = blockIdx.x, d = threadIdx.x;   // 32 x 128
  float s1 = 0.f, s2 = 0.f;
  for (int c = 0; c < cnt; ++c){
    size_t pi = (((size_t)b*cnt + c)*128 + d)*2;
    s1 += part[pi]; s2 += part[pi+1];
  }
  float mean = s1 * 1e-3f;
  float var  = s2 * 1e-3f - mean*mean;
  float a = g[d] * rsqrtf(var + 1e-5f);
  na[b*128 + d] = a; nc[b*128 + d] = beta[d] - mean*a;
}

// ---------------- final apply: dout = x*na+nc ----------------
__global__ __launch_bounds__(256) void k_fapply(
  const float* __restrict__ x, const float* __restrict__ na,
  const float* __restrict__ nc, float* __restrict__ dout){
  int blk = blockIdx.x, tid = threadIdx.x;
  int b = blk / 125;
  size_t base = (size_t)blk*1024 + tid*4;
  int d0 = (tid*4) & 127;
  f32x4 v = *(const f32x4*)&x[base];
  f32x4 o;
#pragma unroll
  for (int e=0;e<4;e++) o[e] = v[e]*na[b*128 + d0 + e] + nc[b*128 + d0 + e];
  *(f32x4*)&dout[base] = o;
}

// ---------------- fused QKV GEMM (+inline norm2 of prev layer) ----------------
// grid (512, 2): x = b*16 + t(64 rows), y: 0=Q->sigq, 1=KV->Zc
template<int NORM>
__global__ __launch_bounds__(256) void k_qkv(
  const unsigned short* __restrict__ xb, const float* __restrict__ x,
  const float* __restrict__ na2, const float* __restrict__ nc2,
  const unsigned short* __restrict__ Wqb, const unsigned short* __restrict__ Wkb,
  const unsigned short* __restrict__ Wvb,
  unsigned short* __restrict__ sigq, unsigned short* __restrict__ Zc)
{
  __shared__ unsigned short LA[2*2048];          // [buf][4][64][8]
  __shared__ unsigned short LB[2][4][256][8];
  __shared__ float sna[128], snc[128];
  int tid = threadIdx.x, wid = tid>>6, lane = tid&63;
  int l15 = lane&15, lg = lane>>4;
  int wm = wid>>1, wn = wid&1;
  int bt = blockIdx.x, b = bt>>4, t = bt&15;
  int kv = blockIdx.y;
  int lrow = t*64 + lane; if (lrow > 999) lrow = 999;
  size_t arow = (size_t)(b*1000 + lrow);

  if (NORM){
    if (tid < 128){ sna[tid] = na2[b*128 + tid]; snc[tid] = nc2[b*128 + tid]; }
    __syncthreads();
  }

  f32x4 zf = {0.f,0.f,0.f,0.f};
  f32x4 acc[2][4], acc2[2][4];
#pragma unroll
  for (int i=0;i<2;i++)
#pragma unroll
    for (int j=0;j<4;j++){ acc[i][j] = zf; acc2[i][j] = zf; }

  auto stage = [&](int kk, int buf){
    int k0 = kk*32;
    if (NORM){
      const float* p = x + arow*128 + k0 + wid*8;
      f32x4 v0 = *(const f32x4*)p;
      f32x4 v1 = *(const f32x4*)(p + 4);
      bf16x8 w;
#pragma unroll
      for (int e=0;e<4;e++){
        int k = k0 + wid*8;
        w[e]   = (short)f2b(v0[e]*sna[k+e]   + snc[k+e]);
        w[4+e] = (short)f2b(v1[e]*sna[k+4+e] + snc[k+4+e]);
      }
      *(bf16x8*)&LA[buf*2048 + wid*512 + lane*8] = w;
    } else {
      gl16(xb + arow*128 + k0 + wid*8, &LA[buf*2048 + wid*512]);
    }
    if (kv == 0){
#pragma unroll
      for (int t2=0;t2<2;++t2){
        int e = wid + t2*4, g2 = e>>1, nb = e&1;
        gl16(Wqb + (size_t)(nb*64+lane)*128 + k0 + g2*8, &LB[buf][g2][nb*64][0]);
      }
    } else {
#pragma unroll
      for (int t2=0;t2<4;++t2){
        int e = wid + t2*4, g2 = e&3, nb = e>>2;
        const unsigned short* src = (nb < 2)
          ? Wkb + (size_t)(nb*64+lane)*128 + k0 + g2*8
          : Wvb + (size_t)((nb-2)*64+lane)*128 + k0 + g2*8;
        gl16(src, &LB[buf][g2][nb*64][0]);
      }
    }
  };
  auto compute = [&](int buf){
    bf16x8 af[2];
#pragma unroll
    for (int i=0;i<2;i++){
      int row = wm*32 + i*16 + l15;
      af[i] = *(const bf16x8*)&LA[buf*2048 + lg*512 + row*8];
    }
#pragma unroll
    for (int j=0;j<4;j++){
      bf16x8 bq = *(const bf16x8*)&LB[buf][lg][wn*64 + j*16 + l15][0];
#pragma unroll
      for (int i=0;i<2;i++) acc[i][j] = mfma16(af[i], bq, acc[i][j]);
      if (kv){
        bf16x8 bv = *(const bf16x8*)&LB[buf][lg][128 + wn*64 + j*16 + l15][0];
#pragma unroll
        for (int i=0;i<2;i++) acc2[i][j] = mfma16(af[i], bv, acc2[i][j]);
      }
    }
  };

  stage(0, 0);
  __syncthreads();
  for (int kk = 0; kk < 4; ++kk){
    int buf = kk & 1;
    if (kk < 3) stage(kk+1, buf^1);
    compute(buf);
    __syncthreads();
  }

#pragma unroll
  for (int i=0;i<2;i++){
    int m4 = t*64 + wm*32 + i*16 + lg*4;
    if (m4 >= 1000) continue;
#pragma unroll
    for (int j=0;j<4;j++){
      int col = wn*64 + j*16 + l15;
      if (kv == 0){
#pragma unroll
        for (int r=0;r<4;r++)
          sigq[(size_t)(b*1000 + m4 + r)*128 + col] = f2b(1.f/(1.f + __expf(-acc[i][j][r])));
      } else {
        s16x4 pv, pk;
#pragma unroll
        for (int r=0;r<4;r++){
          float ek = __expf(acc[i][j][r]);
          pk[r] = (short)f2b(ek);
          pv[r] = (short)f2b(ek * acc2[i][j][r]);
        }
        size_t base = ((size_t)(b*128 + (m4>>3))*256 + col)*8 + ((m4>>2)&1)*4;
        *(s16x4*)&Zc[base] = pv;
        *(s16x4*)&Zc[base + 1024] = pk;
      }
    }
  }
}

// ---------------- fused attention v3: BARRIER-FREE, LDS-FREE ----------------
// grid (16,32), 256 thr = 4 independent waves; wave owns 16 rows (n0 = t*64+wid*16)
// and ALL 256 cols: accB (bias cols 0..127) + accD (denom 128..255) in-register.
// A frag: direct load db16[row][k] + exp in reg (A-operand layout row=l15).
// B frag: direct load from chunked Zc (col=l15); sibling waves share B -> L1 hits.
// Epilogue fully in-register (bias & denom live in the SAME lane).
template<int NORM, int USE16>
__global__ __launch_bounds__(256) void k_attn(
  const float* __restrict__ dist, const unsigned short* __restrict__ db16,
  const unsigned short* __restrict__ Zc, const unsigned short* __restrict__ sigq,
  float* __restrict__ x, float* __restrict__ partA,
  const float* __restrict__ na2, const float* __restrict__ nc2,
  const float* __restrict__ log_scale, const float* __restrict__ alpha, int layer)
{
  int tid = threadIdx.x, wid = tid>>6, lane = tid&63;
  int l15 = lane&15, lg = lane>>4;
  int bb = blockIdx.y, t = blockIdx.x;
  int n0 = t*64 + wid*16;
  float sc = log_scale[0]*alpha[layer];
  const unsigned short* Zb = Zc + ((size_t)bb << 18);
  int an = n0 + l15; if (an > 999) an = 999;         // A-operand row = l15
  const size_t drow = (size_t)(bb*1000 + an);

  f32x4 zf = {0.f,0.f,0.f,0.f};
  f32x4 accB[8], accD[8];
#pragma unroll
  for (int j=0;j<8;j++){ accB[j] = zf; accD[j] = zf; }

#pragma unroll 2
  for (int kk = 0; kk < 32; ++kk){
    int k0 = kk*32 + lg*8;
    bf16x8 af;
    if (USE16){
      bf16x8 ar = *(const bf16x8*)(db16 + drow*1024 + k0);
#pragma unroll
      for (int e=0;e<8;e++) af[e] = (short)f2b(__expf(sc*b2f((unsigned short)ar[e])));
    } else {
      const float* dp = dist + drow*1000;
      if (k0 + 8 <= 1000){
        f32x4 a0 = *(const f32x4*)(dp + k0);
        f32x4 a1 = *(const f32x4*)(dp + k0 + 4);
#pragma unroll
        for (int e=0;e<4;e++){
          af[e]   = (short)f2b(__expf(sc*a0[e]));
          af[4+e] = (short)f2b(__expf(sc*a1[e]));
        }
      } else {
#pragma unroll
        for (int e=0;e<8;e++){
          int m = k0 + e; if (m > 999) m = 999;
          af[e] = (short)f2b(__expf(sc*dp[m]));
        }
      }
    }
    const unsigned short* zk = Zb + ((size_t)(kk*4 + lg))*2048;  // *256*8
#pragma unroll
    for (int j=0;j<8;j++){
      bf16x8 bqB = *(const bf16x8*)(zk + (j*16 + l15)*8);
      bf16x8 bqD = *(const bf16x8*)(zk + (128 + j*16 + l15)*8);
      accB[j] = mfma16(af, bqB, accB[j]);
      accD[j] = mfma16(af, bqD, accD[j]);
    }
  }

  // epilogue: rows n0 + lg*4 + r, cols l15 + 16j — all in-register
  float nav[8], ncv[8];
  if (NORM){
#pragma unroll
    for (int j=0;j<8;j++){
      int d = j*16 + l15;
      nav[j] = na2[bb*128 + d]; ncv[j] = nc2[bb*128 + d];
    }
  }
  float s1[8] = {0,0,0,0,0,0,0,0}, s2[8] = {0,0,0,0,0,0,0,0};
#pragma unroll
  for (int r=0;r<4;r++){
    int n = n0 + lg*4 + r;
    if (n < 1000){
      size_t rowi = ((size_t)bb*1000 + n)*128;
#pragma unroll
      for (int j=0;j<8;j++){
        int d = j*16 + l15;
        float xv = x[rowi + d];
        if (NORM) xv = xv*nav[j] + ncv[j];
        float y = xv + b2f(sigq[rowi + d]) * accB[j][r] / accD[j][r];
        x[rowi + d] = y;
        s1[j] += y; s2[j] += y*y;
      }
    }
  }
#pragma unroll
  for (int j=0;j<8;j++){
    s1[j] += __shfl_xor(s1[j], 16); s2[j] += __shfl_xor(s2[j], 16);
    s1[j] += __shfl_xor(s1[j], 32); s2[j] += __shfl_xor(s2[j], 32);
  }
  if (lg == 0){
#pragma unroll
    for (int j=0;j<8;j++){
      int d = j*16 + l15;
      size_t pi = (((size_t)bb*64 + t*4 + wid)*128 + d)*2;
      partA[pi] = s1[j]; partA[pi+1] = s2[j];
    }
  }
}

// ---------------- FF1 + fused norm1 ----------------
// grid 512, 512 thr, BN=512, K=128; side out: x1 = inorm1(x) f32
__global__ __launch_bounds__(512) void k_ff1(
  const float* __restrict__ x, const float* __restrict__ partA,
  const float* __restrict__ g1, const float* __restrict__ b1,
  const unsigned short* __restrict__ W1b, const float* __restrict__ bw1,
  float* __restrict__ x1, unsigned short* __restrict__ h1)
{
  __shared__ unsigned short LA[2][4][64][8];
  __shared__ unsigned short LB[2][4][512][8];
  __shared__ float sna[128], snc[128];
  int tid = threadIdx.x, wid = tid>>6, lane = tid&63;
  int l15 = lane&15, lg = lane>>4;
  int wm = wid>>2, wn = wid&3;
  int bt = blockIdx.x, b = bt>>4, t = bt&15;

  if (tid < 128){
    float s1 = 0.f, s2 = 0.f;
    for (int c = 0; c < 64; ++c){
      size_t pi = (((size_t)b*64 + c)*128 + tid)*2;
      s1 += partA[pi]; s2 += partA[pi+1];
    }
    float mean = s1 * 1e-3f;
    float var  = s2 * 1e-3f - mean*mean;
    float a = g1[tid] * rsqrtf(var + 1e-5f);
    sna[tid] = a; snc[tid] = b1[tid] - mean*a;
  }
  __syncthreads();

  f32x4 zf = {0.f,0.f,0.f,0.f};
  f32x4 acc[2][8];
#pragma unroll
  for (int i=0;i<2;i++)
#pragma unroll
    for (int j=0;j<8;j++) acc[i][j] = zf;

  auto stage = [&](int kk, int buf){
    int k0 = kk*32;
    if (tid < 256){
      int row = tid & 63, g2 = tid >> 6;
      int lr = t*64 + row;
      int rr = lr > 999 ? 999 : lr;
      const float* p = x + ((size_t)(b*1000 + rr))*128 + k0 + g2*8;
      f32x4 v0 = *(const f32x4*)p;
      f32x4 v1 = *(const f32x4*)(p + 4);
      f32x4 o0, o1;
      bf16x8 w;
#pragma unroll
      for (int e=0;e<4;e++){
        int k = k0 + g2*8;
        o0[e] = v0[e]*sna[k+e]   + snc[k+e];
        o1[e] = v1[e]*sna[k+4+e] + snc[k+4+e];
        w[e]   = (short)f2b(o0[e]);
        w[4+e] = (short)f2b(o1[e]);
      }
      *(bf16x8*)&LA[buf][g2][row][0] = w;
      if (lr < 1000){
        float* q = x1 + ((size_t)(b*1000 + lr))*128 + k0 + g2*8;
        *(f32x4*)q = o0; *(f32x4*)(q+4) = o1;
      }
    }
#pragma unroll
    for (int t2=0;t2<4;++t2){
      int e = wid*4 + t2;
      int g2 = e & 3, nb = e >> 2;
      gl16(W1b + (size_t)(nb*64 + lane)*128 + k0 + g2*8, &LB[buf][g2][nb*64][0]);
    }
  };
  auto compute = [&](int buf){
    bf16x8 af[2];
#pragma unroll
    for (int i=0;i<2;i++) af[i] = *(const bf16x8*)&LA[buf][lg][wm*32 + i*16 + l15][0];
#pragma unroll
    for (int j=0;j<8;j++){
      bf16x8 bq = *(const bf16x8*)&LB[buf][lg][wn*128 + j*16 + l15][0];
#pragma unroll
      for (int i=0;i<2;i++) acc[i][j] = mfma16(af[i], bq, acc[i][j]);
    }
  };

  stage(0, 0);
  __syncthreads();
  for (int kk = 0; kk < 4; ++kk){
    int buf = kk & 1;
    if (kk < 3) stage(kk+1, buf^1);
    compute(buf);
    __syncthreads();
  }

#pragma unroll
  for (int i=0;i<2;i++){
    int m4 = t*64 + wm*32 + i*16 + lg*4;
    if (m4 >= 1000) continue;
#pragma unroll
    for (int j=0;j<8;j++){
      int col = wn*128 + j*16 + l15;
      float bz = bw1[col];
#pragma unroll
      for (int r=0;r<4;r++){
        float v = acc[i][j][r] + bz;
        h1[(size_t)(b*1000 + m4 + r)*512 + col] = f2b(v > 0.f ? v : 0.f);
      }
    }
  }
}

// ---------------- FF2 + residual(f32) + stats ----------------
// grid 512, K=512, BK=64 (8 steps)
__global__ __launch_bounds__(256) void k_ff2(
  const unsigned short* __restrict__ h1, const unsigned short* __restrict__ W2b,
  const float* __restrict__ bw2, const float* __restrict__ x1,
  float* __restrict__ x, float* __restrict__ partF)
{
  __shared__ unsigned short LA[2][8][64][8];
  __shared__ unsigned short LB[2][8][128][8];
  int tid = threadIdx.x, wid = tid>>6, lane = tid&63;
  int l15 = lane&15, lg = lane>>4;
  int wm = wid>>1, wn = wid&1;
  int bt = blockIdx.x, b = bt>>4, t = bt&15;
  int lrow = t*64 + lane; if (lrow > 999) lrow = 999;
  size_t arow = (size_t)(b*1000 + lrow);

  f32x4 zf = {0.f,0.f,0.f,0.f};
  f32x4 acc[2][4];
#pragma unroll
  for (int i=0;i<2;i++)
#pragma unroll
    for (int j=0;j<4;j++) acc[i][j] = zf;

  auto stage = [&](int kk, int buf){
    int k0 = kk*64;
#pragma unroll
    for (int t2=0;t2<2;++t2){
      int g2 = wid + t2*4;
      gl16(h1 + arow*512 + k0 + g2*8, &LA[buf][g2][0][0]);
    }
#pragma unroll
    for (int t2=0;t2<4;++t2){
      int e = wid*4 + t2;
      int g2 = e >> 1, nb = e & 1;
      gl16(W2b + (size_t)(nb*64 + lane)*512 + k0 + g2*8, &LB[buf][g2][nb*64][0]);
    }
  };
  auto compute = [&](int buf){
#pragma unroll
    for (int ks=0; ks<2; ++ks){
      bf16x8 af[2];
#pragma unroll
      for (int i=0;i<2;i++) af[i] = *(const bf16x8*)&LA[buf][ks*4+lg][wm*32 + i*16 + l15][0];
#pragma unroll
      for (int j=0;j<4;j++){
        bf16x8 bq = *(const bf16x8*)&LB[buf][ks*4+lg][wn*64 + j*16 + l15][0];
#pragma unroll
        for (int i=0;i<2;i++) acc[i][j] = mfma16(af[i], bq, acc[i][j]);
      }
    }
  };

  stage(0, 0);
  __syncthreads();
  for (int kk = 0; kk < 8; ++kk){
    int buf = kk & 1;
    if (kk < 7) stage(kk+1, buf^1);
    compute(buf);
    __syncthreads();
  }

  float s1[4] = {0.f,0.f,0.f,0.f}, s2[4] = {0.f,0.f,0.f,0.f};
#pragma unroll
  for (int i=0;i<2;i++){
    int m4 = t*64 + wm*32 + i*16 + lg*4;
    if (m4 >= 1000) continue;
#pragma unroll
    for (int j=0;j<4;j++){
      int col = wn*64 + j*16 + l15;
      float bz = bw2[col];
#pragma unroll
      for (int r=0;r<4;r++){
        size_t idx = (size_t)(b*1000 + m4 + r)*128 + col;
        float y = acc[i][j][r] + bz + x1[idx];
        x[idx] = y;
        s1[j] += y; s2[j] += y*y;
      }
    }
  }
#pragma unroll
  for (int j=0;j<4;j++){
    s1[j] += __shfl_xor(s1[j], 16); s2[j] += __shfl_xor(s2[j], 16);
    s1[j] += __shfl_xor(s1[j], 32); s2[j] += __shfl_xor(s2[j], 32);
  }
  if (lg == 0){
#pragma unroll
    for (int j=0;j<4;j++){
      int d = wn*64 + j*16 + l15;
      size_t pi = (((size_t)b*32 + t*2 + wm)*128 + d)*2;
      partF[pi] = s1[j]; partF[pi+1] = s2[j];
    }
  }
}

extern "C" void kernel_launch(void* const* d_in, const int* in_sizes, int n_in,
                              void* d_out, int out_size, void* d_ws, size_t ws_size,
                              hipStream_t stream) {
  const float* data = (const float*)d_in[0];
  const float* dist = (const float*)d_in[1];
  const float* log_scale = (const float*)d_in[2];
  const float* We = (const float*)d_in[3];
  const float* be = (const float*)d_in[4];
  const float* Wq = (const float*)d_in[5];
  const float* Wk = (const float*)d_in[6];
  const float* Wv = (const float*)d_in[7];
  const float* g1 = (const float*)d_in[8];
  const float* b1 = (const float*)d_in[9];
  const float* W1 = (const float*)d_in[10];
  const float* bw1 = (const float*)d_in[11];
  const float* W2 = (const float*)d_in[12];
  const float* bw2 = (const float*)d_in[13];
  const float* g2 = (const float*)d_in[14];
  const float* b2 = (const float*)d_in[15];
  const float* alpha = (const float*)d_in[16];
  float* dout = (float*)d_out;

  char* ws = (char*)d_ws;
  size_t off = 0;
  auto alloc = [&](size_t bytes) -> void* {
    void* p = ws + off; off += (bytes + 255) & ~(size_t)255; return p;
  };
  unsigned short* xb  = (unsigned short*)alloc(8192000);    // [32000][128] bf16
  float* x            = (float*)alloc(16384000);            // [32000][128] f32
  unsigned short* sigq= (unsigned short*)alloc(8192000);    // [32000][128] bf16
  unsigned short* Zc  = (unsigned short*)alloc(16777216);   // [32][128][256][8] bf16
  unsigned short* h1  = (unsigned short*)alloc(32768000);   // [32000][512] bf16
  float* x1           = (float*)alloc(16384000);            // [32000][128] f32
  float* partA        = (float*)alloc(2097152);             // [32][64][128][2]
  float* partF        = (float*)alloc(1048576);             // [32][32][128][2]
  float* na2          = (float*)alloc(16384);
  float* nc2          = (float*)alloc(16384);
  unsigned short* wqb = (unsigned short*)alloc(196608);
  unsigned short* wkb = (unsigned short*)alloc(196608);
  unsigned short* wvb = (unsigned short*)alloc(196608);
  unsigned short* w1b = (unsigned short*)alloc(786432);
  unsigned short* w2b = (unsigned short*)alloc(786432);
  if (off > ws_size) return;
  unsigned short* db16p = nullptr;
  if (ws_size >= off + 131072256) db16p = (unsigned short*)alloc(131072000); // [32000][1024] bf16

  hipMemsetAsync(Zc, 0, 16777216, stream);
  k_cvt5<<<4224, 256, 0, stream>>>(Wq, Wk, Wv, W1, W2, wqb, wkb, wvb, w1b, w2b);
  if (db16p) k_cvtdist<<<16000, 256, 0, stream>>>(dist, db16p);
  k_embed<<<16000, 256, 0, stream>>>(data, We, be, x, xb);

  for (int i = 0; i < LCOUNT; ++i){
    if (i > 0)
      k_scale<<<32, 128, 0, stream>>>(partF, 32, g2 + (i-1)*128, b2 + (i-1)*128, na2, nc2);
    if (i == 0)
      k_qkv<0><<<dim3(512,2), 256, 0, stream>>>(xb, x, nullptr, nullptr,
                                                wqb + i*16384, wkb + i*16384, wvb + i*16384,
                                                sigq, Zc);
    else
      k_qkv<1><<<dim3(512,2), 256, 0, stream>>>(nullptr, x, na2, nc2,
                                                wqb + i*16384, wkb + i*16384, wvb + i*16384,
                                                sigq, Zc);
    if (i == 0){
      if (db16p) k_attn<0,1><<<dim3(16,32), 256, 0, stream>>>(dist, db16p, Zc, sigq, x, partA,
                                                              nullptr, nullptr, log_scale, alpha, i);
      else       k_attn<0,0><<<dim3(16,32), 256, 0, stream>>>(dist, nullptr, Zc, sigq, x, partA,
                                                              nullptr, nullptr, log_scale, alpha, i);
    } else {
      if (db16p) k_attn<1,1><<<dim3(16,32), 256, 0, stream>>>(dist, db16p, Zc, sigq, x, partA,
                                                              na2, nc2, log_scale, alpha, i);
      else       k_attn<1,0><<<dim3(16,32), 256, 0, stream>>>(dist, nullptr, Zc, sigq, x, partA,
                                                              na2, nc2, log_scale, alpha, i);
    }
    k_ff1<<<512, 512, 0, stream>>>(x, partA, g1 + i*128, b1 + i*128,
                                   w1b + i*65536, bw1 + i*512, x1, h1);
    k_ff2<<<512, 256, 0, stream>>>(h1, w2b + i*65536, bw2 + i*128, x1, x, partF);
  }
  k_scale<<<32, 128, 0, stream>>>(partF, 32, g2 + 5*128, b2 + 5*128, na2, nc2);
  k_fapply<<<4000, 256, 0, stream>>>(x, na2, nc2, dout);
}

// Round 16
// 821.236 us; speedup vs baseline: 1.3296x; 1.3296x over previous
//
#include <hip/hip_runtime.h>
#include <hip/hip_bf16.h>

typedef __attribute__((ext_vector_type(4))) float f32x4;
typedef __attribute__((ext_vector_type(8))) short bf16x8;
typedef __attribute__((ext_vector_type(4))) short s16x4;

#define LCOUNT 6

static __device__ __forceinline__ unsigned short f2b(float f){
  __hip_bfloat16 h = __float2bfloat16(f);
  return __builtin_bit_cast(unsigned short, h);
}
static __device__ __forceinline__ float b2f(unsigned short u){
  unsigned int x = ((unsigned int)u) << 16;
  return __builtin_bit_cast(float, x);
}
static __device__ __forceinline__ void gl16(const void* g, void* l){
  __builtin_amdgcn_global_load_lds(
      (const __attribute__((address_space(1))) void*)g,
      (__attribute__((address_space(3))) void*)l, 16, 0, 0);
}
static __device__ __forceinline__ f32x4 mfma16(bf16x8 a, bf16x8 b, f32x4 c){
  return __builtin_amdgcn_mfma_f32_16x16x32_bf16(a, b, c, 0, 0, 0);
}

// ---------------- setup kernels ----------------
__global__ void k_cvt5(const float* __restrict__ Wq, const float* __restrict__ Wk,
                       const float* __restrict__ Wv, const float* __restrict__ W1,
                       const float* __restrict__ W2,
                       unsigned short* __restrict__ wqb, unsigned short* __restrict__ wkb,
                       unsigned short* __restrict__ wvb, unsigned short* __restrict__ w1b,
                       unsigned short* __restrict__ w2b){
  int i = blockIdx.x*256 + threadIdx.x;
  if (i < 98304) wqb[i] = f2b(Wq[i]);
  else if (i < 196608) wkb[i-98304] = f2b(Wk[i-98304]);
  else if (i < 294912) wvb[i-196608] = f2b(Wv[i-196608]);
  else if (i < 688128) w1b[i-294912] = f2b(W1[i-294912]);
  else w2b[i-688128] = f2b(W2[i-688128]);
}

__global__ void k_cvtdist(const float* __restrict__ dist, unsigned short* __restrict__ db){
  int t = blockIdx.x*256 + threadIdx.x;
  int row = t >> 7, ch = t & 127;
  bf16x8 w;
  if (ch >= 125){
#pragma unroll
    for (int e=0;e<8;e++) w[e] = 0;
  } else {
    const float* p = dist + (size_t)row*1000 + ch*8;
    f32x4 a = *(const f32x4*)p;
    f32x4 b = *(const f32x4*)(p + 4);
#pragma unroll
    for (int e=0;e<4;e++){ w[e] = (short)f2b(a[e]); w[4+e] = (short)f2b(b[e]); }
  }
  *(bf16x8*)&db[(size_t)row*1024 + ch*8] = w;
}

__global__ void k_embed(const float* __restrict__ data, const float* __restrict__ We,
                        const float* __restrict__ be, float* __restrict__ x,
                        unsigned short* __restrict__ xb){
  int idx = blockIdx.x*256 + threadIdx.x;
  int d = idx & 127, bn = idx >> 7;
  float v = data[bn*2]*We[d*2] + data[bn*2+1]*We[d*2+1] + be[d];
  x[idx] = v; xb[idx] = f2b(v);
}

// ---------------- norm-scale reduce: part -> na,nc [32][128] ----------------
__global__ void k_scale(const float* __restrict__ part, int cnt,
                        const float* __restrict__ g, const float* __restrict__ beta,
                        float* __restrict__ na, float* __restrict__ nc){
  int b = blockIdx.x, d = threadIdx.x;   // 32 x 128
  float s1 = 0.f, s2 = 0.f;
  for (int c = 0; c < cnt; ++c){
    size_t pi = (((size_t)b*cnt + c)*128 + d)*2;
    s1 += part[pi]; s2 += part[pi+1];
  }
  float mean = s1 * 1e-3f;
  float var  = s2 * 1e-3f - mean*mean;
  float a = g[d] * rsqrtf(var + 1e-5f);
  na[b*128 + d] = a; nc[b*128 + d] = beta[d] - mean*a;
}

// ---------------- final apply: dout = x*na+nc ----------------
__global__ __launch_bounds__(256) void k_fapply(
  const float* __restrict__ x, const float* __restrict__ na,
  const float* __restrict__ nc, float* __restrict__ dout){
  int blk = blockIdx.x, tid = threadIdx.x;
  int b = blk / 125;
  size_t base = (size_t)blk*1024 + tid*4;
  int d0 = (tid*4) & 127;
  f32x4 v = *(const f32x4*)&x[base];
  f32x4 o;
#pragma unroll
  for (int e=0;e<4;e++) o[e] = v[e]*na[b*128 + d0 + e] + nc[b*128 + d0 + e];
  *(f32x4*)&dout[base] = o;
}

// ---------------- fused QKV GEMM (+inline norm2 of prev layer) ----------------
// grid (512, 2): x = b*16 + t(64 rows), y: 0=Q->sigq, 1=KV->Zc
template<int NORM>
__global__ __launch_bounds__(256) void k_qkv(
  const unsigned short* __restrict__ xb, const float* __restrict__ x,
  const float* __restrict__ na2, const float* __restrict__ nc2,
  const unsigned short* __restrict__ Wqb, const unsigned short* __restrict__ Wkb,
  const unsigned short* __restrict__ Wvb,
  unsigned short* __restrict__ sigq, unsigned short* __restrict__ Zc)
{
  __shared__ unsigned short LA[2*2048];          // [buf][4][64][8]
  __shared__ unsigned short LB[2][4][256][8];
  __shared__ float sna[128], snc[128];
  int tid = threadIdx.x, wid = tid>>6, lane = tid&63;
  int l15 = lane&15, lg = lane>>4;
  int wm = wid>>1, wn = wid&1;
  int bt = blockIdx.x, b = bt>>4, t = bt&15;
  int kv = blockIdx.y;
  int lrow = t*64 + lane; if (lrow > 999) lrow = 999;
  size_t arow = (size_t)(b*1000 + lrow);

  if (NORM){
    if (tid < 128){ sna[tid] = na2[b*128 + tid]; snc[tid] = nc2[b*128 + tid]; }
    __syncthreads();
  }

  f32x4 zf = {0.f,0.f,0.f,0.f};
  f32x4 acc[2][4], acc2[2][4];
#pragma unroll
  for (int i=0;i<2;i++)
#pragma unroll
    for (int j=0;j<4;j++){ acc[i][j] = zf; acc2[i][j] = zf; }

  auto stage = [&](int kk, int buf){
    int k0 = kk*32;
    if (NORM){
      const float* p = x + arow*128 + k0 + wid*8;
      f32x4 v0 = *(const f32x4*)p;
      f32x4 v1 = *(const f32x4*)(p + 4);
      bf16x8 w;
#pragma unroll
      for (int e=0;e<4;e++){
        int k = k0 + wid*8;
        w[e]   = (short)f2b(v0[e]*sna[k+e]   + snc[k+e]);
        w[4+e] = (short)f2b(v1[e]*sna[k+4+e] + snc[k+4+e]);
      }
      *(bf16x8*)&LA[buf*2048 + wid*512 + lane*8] = w;
    } else {
      gl16(xb + arow*128 + k0 + wid*8, &LA[buf*2048 + wid*512]);
    }
    if (kv == 0){
#pragma unroll
      for (int t2=0;t2<2;++t2){
        int e = wid + t2*4, g2 = e>>1, nb = e&1;
        gl16(Wqb + (size_t)(nb*64+lane)*128 + k0 + g2*8, &LB[buf][g2][nb*64][0]);
      }
    } else {
#pragma unroll
      for (int t2=0;t2<4;++t2){
        int e = wid + t2*4, g2 = e&3, nb = e>>2;
        const unsigned short* src = (nb < 2)
          ? Wkb + (size_t)(nb*64+lane)*128 + k0 + g2*8
          : Wvb + (size_t)((nb-2)*64+lane)*128 + k0 + g2*8;
        gl16(src, &LB[buf][g2][nb*64][0]);
      }
    }
  };
  auto compute = [&](int buf){
    bf16x8 af[2];
#pragma unroll
    for (int i=0;i<2;i++){
      int row = wm*32 + i*16 + l15;
      af[i] = *(const bf16x8*)&LA[buf*2048 + lg*512 + row*8];
    }
#pragma unroll
    for (int j=0;j<4;j++){
      bf16x8 bq = *(const bf16x8*)&LB[buf][lg][wn*64 + j*16 + l15][0];
#pragma unroll
      for (int i=0;i<2;i++) acc[i][j] = mfma16(af[i], bq, acc[i][j]);
      if (kv){
        bf16x8 bv = *(const bf16x8*)&LB[buf][lg][128 + wn*64 + j*16 + l15][0];
#pragma unroll
        for (int i=0;i<2;i++) acc2[i][j] = mfma16(af[i], bv, acc2[i][j]);
      }
    }
  };

  stage(0, 0);
  __syncthreads();
  for (int kk = 0; kk < 4; ++kk){
    int buf = kk & 1;
    if (kk < 3) stage(kk+1, buf^1);
    compute(buf);
    __syncthreads();
  }

#pragma unroll
  for (int i=0;i<2;i++){
    int m4 = t*64 + wm*32 + i*16 + lg*4;
    if (m4 >= 1000) continue;
#pragma unroll
    for (int j=0;j<4;j++){
      int col = wn*64 + j*16 + l15;
      if (kv == 0){
#pragma unroll
        for (int r=0;r<4;r++)
          sigq[(size_t)(b*1000 + m4 + r)*128 + col] = f2b(1.f/(1.f + __expf(-acc[i][j][r])));
      } else {
        s16x4 pv, pk;
#pragma unroll
        for (int r=0;r<4;r++){
          float ek = __expf(acc[i][j][r]);
          pk[r] = (short)f2b(ek);
          pv[r] = (short)f2b(ek * acc2[i][j][r]);
        }
        size_t base = ((size_t)(b*128 + (m4>>3))*256 + col)*8 + ((m4>>2)&1)*4;
        *(s16x4*)&Zc[base] = pv;
        *(s16x4*)&Zc[base + 1024] = pk;
      }
    }
  }
}

// ---------------- fused attention (+inline norm2) + stats ----------------
// grid 512 linear, XCD-swizzled decode: id = (bb&7) + 8*(t + 16*(bb>>3))
// -> all 16 row-tiles of a batch land on ONE XCD (Zc panel + db16 L2-resident)
// BK=64 (8 chunks/step, 16 steps), 4 waves, gl16 B-staging, 1 barrier/step (R10)
template<int NORM, int USE16>
__global__ __launch_bounds__(256) void k_attn(
  const float* __restrict__ dist, const unsigned short* __restrict__ db16,
  const unsigned short* __restrict__ Zc, const unsigned short* __restrict__ sigq,
  float* __restrict__ x, float* __restrict__ partA,
  const float* __restrict__ na2, const float* __restrict__ nc2,
  const float* __restrict__ log_scale, const float* __restrict__ alpha, int layer)
{
  union SM {
    struct { unsigned short A[2][8][64][8]; unsigned short B[2][8][256][8]; } st;
    float den[64][128];
  };
  __shared__ SM sm;
  int tid = threadIdx.x, wid = tid>>6, lane = tid&63;
  int l15 = lane&15, lg = lane>>4;
  int lid = blockIdx.x;
  int xcd = lid & 7, rest = lid >> 3;
  int t = rest & 15, bb = xcd + 8*(rest >> 4);
  int n0 = t*64;
  float sc = log_scale[0]*alpha[layer];
  const unsigned short* Zb = Zc + ((size_t)bb << 18);
  int an = n0 + lane; if (an > 999) an = 999;     // staging row = lane, chunks {wid, wid+4}
  const size_t drow = (size_t)(bb*1000 + an);

  f32x4 zf = {0.f,0.f,0.f,0.f};
  f32x4 acc[4][4];
#pragma unroll
  for (int i=0;i<4;i++)
#pragma unroll
    for (int j=0;j<4;j++) acc[i][j] = zf;

  auto issueB = [&](int kk, int buf){
#pragma unroll
    for (int t2=0;t2<8;++t2){
      int e = wid + t2*4;            // 0..31 wave-uniform
      int g2 = e >> 2, cb = e & 3;   // chunk 0..7, col-block 0..3
      gl16(Zb + ((size_t)((kk*8 + g2)*256 + cb*64 + lane))*8, &sm.st.B[buf][g2][cb*64][0]);
    }
  };
  auto loadA2 = [&](int kk, float* v0, float* v1){
    int k0 = kk*64 + wid*8;
    int k1 = k0 + 32;                // chunk wid+4
    if (USE16){
      bf16x8 r0 = *(const bf16x8*)(db16 + drow*1024 + k0);
      bf16x8 r1 = *(const bf16x8*)(db16 + drow*1024 + k1);
#pragma unroll
      for (int e=0;e<8;e++){ v0[e] = b2f((unsigned short)r0[e]); v1[e] = b2f((unsigned short)r1[e]); }
    } else {
      const float* dp = dist + drow*1000;
#pragma unroll
      for (int e=0;e<8;e++){
        int m0 = k0 + e; if (m0 > 999) m0 = 999;
        int m1 = k1 + e; if (m1 > 999) m1 = 999;
        v0[e] = dp[m0]; v1[e] = dp[m1];
      }
    }
  };
  auto expwrite2 = [&](const float* v0, const float* v1, int buf){
    bf16x8 w0, w1;
#pragma unroll
    for (int e=0;e<8;e++){
      w0[e] = (short)f2b(__expf(sc*v0[e]));
      w1[e] = (short)f2b(__expf(sc*v1[e]));
    }
    *(bf16x8*)&sm.st.A[buf][wid][lane][0]     = w0;   // contiguous 1KB per wave
    *(bf16x8*)&sm.st.A[buf][wid+4][lane][0]   = w1;
  };
  auto compute = [&](int buf){
#pragma unroll
    for (int ks=0; ks<2; ++ks){
      bf16x8 af[4], bq[4];
#pragma unroll
      for (int i=0;i<4;i++) af[i] = *(const bf16x8*)&sm.st.A[buf][ks*4+lg][i*16 + l15][0];
#pragma unroll
      for (int j=0;j<4;j++) bq[j] = *(const bf16x8*)&sm.st.B[buf][ks*4+lg][wid*64 + j*16 + l15][0];
#pragma unroll
      for (int i=0;i<4;i++)
#pragma unroll
        for (int j=0;j<4;j++)
          acc[i][j] = mfma16(af[i], bq[j], acc[i][j]);
    }
  };

  float av0[8], av1[8];
  issueB(0, 0);
  loadA2(0, av0, av1);
  expwrite2(av0, av1, 0);
  __syncthreads();
  for (int kk = 0; kk < 16; ++kk){
    int buf = kk & 1;
    float nv0[8], nv1[8];
    if (kk < 15){ issueB(kk+1, buf^1); loadA2(kk+1, nv0, nv1); }
    compute(buf);
    if (kk < 15) expwrite2(nv0, nv1, buf^1);
    __syncthreads();
  }

  if (wid >= 2){
#pragma unroll
    for (int i=0;i<4;i++)
#pragma unroll
      for (int j=0;j<4;j++){
        int dcol = (wid-2)*64 + j*16 + l15;
#pragma unroll
        for (int r=0;r<4;r++)
          sm.den[i*16 + lg*4 + r][dcol] = acc[i][j][r];
      }
  }
  __syncthreads();
  if (wid < 2){
    float nav[4], ncv[4];
    if (NORM){
#pragma unroll
      for (int j=0;j<4;j++){
        int d = wid*64 + j*16 + l15;
        nav[j] = na2[bb*128 + d]; ncv[j] = nc2[bb*128 + d];
      }
    }
    float s1[4] = {0.f,0.f,0.f,0.f}, s2[4] = {0.f,0.f,0.f,0.f};
#pragma unroll
    for (int i=0;i<4;i++){
#pragma unroll
      for (int r=0;r<4;r++){
        int n = n0 + i*16 + lg*4 + r;
        if (n < 1000){
          size_t rowi = ((size_t)bb*1000 + n)*128;
#pragma unroll
          for (int j=0;j<4;j++){
            int d = wid*64 + j*16 + l15;
            float xv = x[rowi + d];
            if (NORM) xv = xv*nav[j] + ncv[j];
            float y = xv + b2f(sigq[rowi + d]) * acc[i][j][r] / sm.den[i*16 + lg*4 + r][d];
            x[rowi + d] = y;
            s1[j] += y; s2[j] += y*y;
          }
        }
      }
    }
#pragma unroll
    for (int j=0;j<4;j++){
      s1[j] += __shfl_xor(s1[j], 16); s2[j] += __shfl_xor(s2[j], 16);
      s1[j] += __shfl_xor(s1[j], 32); s2[j] += __shfl_xor(s2[j], 32);
    }
    if (lg == 0){
#pragma unroll
      for (int j=0;j<4;j++){
        int d = wid*64 + j*16 + l15;
        size_t pi = (((size_t)bb*16 + t)*128 + d)*2;
        partA[pi] = s1[j]; partA[pi+1] = s2[j];
      }
    }
  }
}

// ---------------- FF1 + fused norm1 ----------------
// grid 512, 512 thr, BN=512, K=128; side out: x1 = inorm1(x) f32
__global__ __launch_bounds__(512) void k_ff1(
  const float* __restrict__ x, const float* __restrict__ partA,
  const float* __restrict__ g1, const float* __restrict__ b1,
  const unsigned short* __restrict__ W1b, const float* __restrict__ bw1,
  float* __restrict__ x1, unsigned short* __restrict__ h1)
{
  __shared__ unsigned short LA[2][4][64][8];
  __shared__ unsigned short LB[2][4][512][8];
  __shared__ float sna[128], snc[128];
  int tid = threadIdx.x, wid = tid>>6, lane = tid&63;
  int l15 = lane&15, lg = lane>>4;
  int wm = wid>>2, wn = wid&3;
  int bt = blockIdx.x, b = bt>>4, t = bt&15;

  if (tid < 128){
    float s1 = 0.f, s2 = 0.f;
    for (int c = 0; c < 16; ++c){
      size_t pi = (((size_t)b*16 + c)*128 + tid)*2;
      s1 += partA[pi]; s2 += partA[pi+1];
    }
    float mean = s1 * 1e-3f;
    float var  = s2 * 1e-3f - mean*mean;
    float a = g1[tid] * rsqrtf(var + 1e-5f);
    sna[tid] = a; snc[tid] = b1[tid] - mean*a;
  }
  __syncthreads();

  f32x4 zf = {0.f,0.f,0.f,0.f};
  f32x4 acc[2][8];
#pragma unroll
  for (int i=0;i<2;i++)
#pragma unroll
    for (int j=0;j<8;j++) acc[i][j] = zf;

  auto stage = [&](int kk, int buf){
    int k0 = kk*32;
    if (tid < 256){
      int row = tid & 63, g2 = tid >> 6;
      int lr = t*64 + row;
      int rr = lr > 999 ? 999 : lr;
      const float* p = x + ((size_t)(b*1000 + rr))*128 + k0 + g2*8;
      f32x4 v0 = *(const f32x4*)p;
      f32x4 v1 = *(const f32x4*)(p + 4);
      f32x4 o0, o1;
      bf16x8 w;
#pragma unroll
      for (int e=0;e<4;e++){
        int k = k0 + g2*8;
        o0[e] = v0[e]*sna[k+e]   + snc[k+e];
        o1[e] = v1[e]*sna[k+4+e] + snc[k+4+e];
        w[e]   = (short)f2b(o0[e]);
        w[4+e] = (short)f2b(o1[e]);
      }
      *(bf16x8*)&LA[buf][g2][row][0] = w;
      if (lr < 1000){
        float* q = x1 + ((size_t)(b*1000 + lr))*128 + k0 + g2*8;
        *(f32x4*)q = o0; *(f32x4*)(q+4) = o1;
      }
    }
#pragma unroll
    for (int t2=0;t2<4;++t2){
      int e = wid*4 + t2;
      int g2 = e & 3, nb = e >> 2;
      gl16(W1b + (size_t)(nb*64 + lane)*128 + k0 + g2*8, &LB[buf][g2][nb*64][0]);
    }
  };
  auto compute = [&](int buf){
    bf16x8 af[2];
#pragma unroll
    for (int i=0;i<2;i++) af[i] = *(const bf16x8*)&LA[buf][lg][wm*32 + i*16 + l15][0];
#pragma unroll
    for (int j=0;j<8;j++){
      bf16x8 bq = *(const bf16x8*)&LB[buf][lg][wn*128 + j*16 + l15][0];
#pragma unroll
      for (int i=0;i<2;i++) acc[i][j] = mfma16(af[i], bq, acc[i][j]);
    }
  };

  stage(0, 0);
  __syncthreads();
  for (int kk = 0; kk < 4; ++kk){
    int buf = kk & 1;
    if (kk < 3) stage(kk+1, buf^1);
    compute(buf);
    __syncthreads();
  }

#pragma unroll
  for (int i=0;i<2;i++){
    int m4 = t*64 + wm*32 + i*16 + lg*4;
    if (m4 >= 1000) continue;
#pragma unroll
    for (int j=0;j<8;j++){
      int col = wn*128 + j*16 + l15;
      float bz = bw1[col];
#pragma unroll
      for (int r=0;r<4;r++){
        float v = acc[i][j][r] + bz;
        h1[(size_t)(b*1000 + m4 + r)*512 + col] = f2b(v > 0.f ? v : 0.f);
      }
    }
  }
}

// ---------------- FF2 + residual(f32) + stats ----------------
// grid 512, K=512
__global__ __launch_bounds__(256) void k_ff2(
  const unsigned short* __restrict__ h1, const unsigned short* __restrict__ W2b,
  const float* __restrict__ bw2, const float* __restrict__ x1,
  float* __restrict__ x, float* __restrict__ partF)
{
  __shared__ unsigned short LA[2][4][64][8];
  __shared__ unsigned short LB[2][4][128][8];
  int tid = threadIdx.x, wid = tid>>6, lane = tid&63;
  int l15 = lane&15, lg = lane>>4;
  int wm = wid>>1, wn = wid&1;
  int bt = blockIdx.x, b = bt>>4, t = bt&15;
  int lrow = t*64 + lane; if (lrow > 999) lrow = 999;
  size_t arow = (size_t)(b*1000 + lrow);

  f32x4 zf = {0.f,0.f,0.f,0.f};
  f32x4 acc[2][4];
#pragma unroll
  for (int i=0;i<2;i++)
#pragma unroll
    for (int j=0;j<4;j++) acc[i][j] = zf;

  auto stage = [&](int kk, int buf){
    int k0 = kk*32;
    gl16(h1 + arow*512 + k0 + wid*8, &LA[buf][wid][0][0]);
#pragma unroll
    for (int t2=0;t2<2;++t2){
      int e = wid + t2*4, g2 = e>>1, nb = e&1;
      gl16(W2b + (size_t)(nb*64 + lane)*512 + k0 + g2*8, &LB[buf][g2][nb*64][0]);
    }
  };
  auto compute = [&](int buf){
    bf16x8 af[2];
#pragma unroll
    for (int i=0;i<2;i++) af[i] = *(const bf16x8*)&LA[buf][lg][wm*32 + i*16 + l15][0];
#pragma unroll
    for (int j=0;j<4;j++){
      bf16x8 bq = *(const bf16x8*)&LB[buf][lg][wn*64 + j*16 + l15][0];
#pragma unroll
      for (int i=0;i<2;i++) acc[i][j] = mfma16(af[i], bq, acc[i][j]);
    }
  };

  stage(0, 0);
  __syncthreads();
  for (int kk = 0; kk < 16; ++kk){
    int buf = kk & 1;
    if (kk < 15) stage(kk+1, buf^1);
    compute(buf);
    __syncthreads();
  }

  float s1[4] = {0.f,0.f,0.f,0.f}, s2[4] = {0.f,0.f,0.f,0.f};
#pragma unroll
  for (int i=0;i<2;i++){
    int m4 = t*64 + wm*32 + i*16 + lg*4;
    if (m4 >= 1000) continue;
#pragma unroll
    for (int j=0;j<4;j++){
      int col = wn*64 + j*16 + l15;
      float bz = bw2[col];
#pragma unroll
      for (int r=0;r<4;r++){
        size_t idx = (size_t)(b*1000 + m4 + r)*128 + col;
        float y = acc[i][j][r] + bz + x1[idx];
        x[idx] = y;
        s1[j] += y; s2[j] += y*y;
      }
    }
  }
#pragma unroll
  for (int j=0;j<4;j++){
    s1[j] += __shfl_xor(s1[j], 16); s2[j] += __shfl_xor(s2[j], 16);
    s1[j] += __shfl_xor(s1[j], 32); s2[j] += __shfl_xor(s2[j], 32);
  }
  if (lg == 0){
#pragma unroll
    for (int j=0;j<4;j++){
      int d = wn*64 + j*16 + l15;
      size_t pi = (((size_t)b*32 + t*2 + wm)*128 + d)*2;
      partF[pi] = s1[j]; partF[pi+1] = s2[j];
    }
  }
}

extern "C" void kernel_launch(void* const* d_in, const int* in_sizes, int n_in,
                              void* d_out, int out_size, void* d_ws, size_t ws_size,
                              hipStream_t stream) {
  const float* data = (const float*)d_in[0];
  const float* dist = (const float*)d_in[1];
  const float* log_scale = (const float*)d_in[2];
  const float* We = (const float*)d_in[3];
  const float* be = (const float*)d_in[4];
  const float* Wq = (const float*)d_in[5];
  const float* Wk = (const float*)d_in[6];
  const float* Wv = (const float*)d_in[7];
  const float* g1 = (const float*)d_in[8];
  const float* b1 = (const float*)d_in[9];
  const float* W1 = (const float*)d_in[10];
  const float* bw1 = (const float*)d_in[11];
  const float* W2 = (const float*)d_in[12];
  const float* bw2 = (const float*)d_in[13];
  const float* g2 = (const float*)d_in[14];
  const float* b2 = (const float*)d_in[15];
  const float* alpha = (const float*)d_in[16];
  float* dout = (float*)d_out;

  char* ws = (char*)d_ws;
  size_t off = 0;
  auto alloc = [&](size_t bytes) -> void* {
    void* p = ws + off; off += (bytes + 255) & ~(size_t)255; return p;
  };
  unsigned short* xb  = (unsigned short*)alloc(8192000);    // [32000][128] bf16
  float* x            = (float*)alloc(16384000);            // [32000][128] f32
  unsigned short* sigq= (unsigned short*)alloc(8192000);    // [32000][128] bf16
  unsigned short* Zc  = (unsigned short*)alloc(16777216);   // [32][128][256][8] bf16
  unsigned short* h1  = (unsigned short*)alloc(32768000);   // [32000][512] bf16
  float* x1           = (float*)alloc(16384000);            // [32000][128] f32
  float* partA        = (float*)alloc(524288);              // [32][16][128][2]
  float* partF        = (float*)alloc(1048576);             // [32][32][128][2]
  float* na2          = (float*)alloc(16384);
  float* nc2          = (float*)alloc(16384);
  unsigned short* wqb = (unsigned short*)alloc(196608);
  unsigned short* wkb = (unsigned short*)alloc(196608);
  unsigned short* wvb = (unsigned short*)alloc(196608);
  unsigned short* w1b = (unsigned short*)alloc(786432);
  unsigned short* w2b = (unsigned short*)alloc(786432);
  if (off > ws_size) return;
  unsigned short* db16p = nullptr;
  if (ws_size >= off + 131072256) db16p = (unsigned short*)alloc(131072000); // [32000][1024] bf16

  hipMemsetAsync(Zc, 0, 16777216, stream);
  k_cvt5<<<4224, 256, 0, stream>>>(Wq, Wk, Wv, W1, W2, wqb, wkb, wvb, w1b, w2b);
  if (db16p) k_cvtdist<<<16000, 256, 0, stream>>>(dist, db16p);
  k_embed<<<16000, 256, 0, stream>>>(data, We, be, x, xb);

  for (int i = 0; i < LCOUNT; ++i){
    if (i > 0)
      k_scale<<<32, 128, 0, stream>>>(partF, 32, g2 + (i-1)*128, b2 + (i-1)*128, na2, nc2);
    if (i == 0)
      k_qkv<0><<<dim3(512,2), 256, 0, stream>>>(xb, x, nullptr, nullptr,
                                                wqb + i*16384, wkb + i*16384, wvb + i*16384,
                                                sigq, Zc);
    else
      k_qkv<1><<<dim3(512,2), 256, 0, stream>>>(nullptr, x, na2, nc2,
                                                wqb + i*16384, wkb + i*16384, wvb + i*16384,
                                                sigq, Zc);
    if (i == 0){
      if (db16p) k_attn<0,1><<<512, 256, 0, stream>>>(dist, db16p, Zc, sigq, x, partA,
                                                      nullptr, nullptr, log_scale, alpha, i);
      else       k_attn<0,0><<<512, 256, 0, stream>>>(dist, nullptr, Zc, sigq, x, partA,
                                                      nullptr, nullptr, log_scale, alpha, i);
    } else {
      if (db16p) k_attn<1,1><<<512, 256, 0, stream>>>(dist, db16p, Zc, sigq, x, partA,
                                                      na2, nc2, log_scale, alpha, i);
      else       k_attn<1,0><<<512, 256, 0, stream>>>(dist, nullptr, Zc, sigq, x, partA,
                                                      na2, nc2, log_scale, alpha, i);
    }
    k_ff1<<<512, 512, 0, stream>>>(x, partA, g1 + i*128, b1 + i*128,
                                   w1b + i*65536, bw1 + i*512, x1, h1);
    k_ff2<<<512, 256, 0, stream>>>(h1, w2b + i*65536, bw2 + i*128, x1, x, partF);
  }
  k_scale<<<32, 128, 0, stream>>>(partF, 32, g2 + 5*128, b2 + 5*128, na2, nc2);
  k_fapply<<<4000, 256, 0, stream>>>(x, na2, nc2, dout);
}

// Round 17
// 820.148 us; speedup vs baseline: 1.3313x; 1.0013x over previous
//
#include <hip/hip_runtime.h>
#include <hip/hip_bf16.h>

typedef __attribute__((ext_vector_type(4))) float f32x4;
typedef __attribute__((ext_vector_type(8))) short bf16x8;
typedef __attribute__((ext_vector_type(4))) short s16x4;

#define LCOUNT 6

static __device__ __forceinline__ unsigned short f2b(float f){
  __hip_bfloat16 h = __float2bfloat16(f);
  return __builtin_bit_cast(unsigned short, h);
}
static __device__ __forceinline__ float b2f(unsigned short u){
  unsigned int x = ((unsigned int)u) << 16;
  return __builtin_bit_cast(float, x);
}
static __device__ __forceinline__ void gl16(const void* g, void* l){
  __builtin_amdgcn_global_load_lds(
      (const __attribute__((address_space(1))) void*)g,
      (__attribute__((address_space(3))) void*)l, 16, 0, 0);
}
static __device__ __forceinline__ f32x4 mfma16(bf16x8 a, bf16x8 b, f32x4 c){
  return __builtin_amdgcn_mfma_f32_16x16x32_bf16(a, b, c, 0, 0, 0);
}
// batch->XCD affinity decode: blocks of batch bb always land on XCD bb&7
static __device__ __forceinline__ void bdecode(int lid, int& bb, int& t){
  int xcd = lid & 7, rest = lid >> 3;
  t = rest & 15; bb = xcd + 8*(rest >> 4);
}

// ---------------- setup kernels ----------------
__global__ void k_cvt5(const float* __restrict__ Wq, const float* __restrict__ Wk,
                       const float* __restrict__ Wv, const float* __restrict__ W1,
                       const float* __restrict__ W2,
                       unsigned short* __restrict__ wqb, unsigned short* __restrict__ wkb,
                       unsigned short* __restrict__ wvb, unsigned short* __restrict__ w1b,
                       unsigned short* __restrict__ w2b){
  int i = blockIdx.x*256 + threadIdx.x;
  if (i < 98304) wqb[i] = f2b(Wq[i]);
  else if (i < 196608) wkb[i-98304] = f2b(Wk[i-98304]);
  else if (i < 294912) wvb[i-196608] = f2b(Wv[i-196608]);
  else if (i < 688128) w1b[i-294912] = f2b(W1[i-294912]);
  else w2b[i-688128] = f2b(W2[i-688128]);
}

__global__ void k_cvtdist(const float* __restrict__ dist, unsigned short* __restrict__ db){
  int t = blockIdx.x*256 + threadIdx.x;
  int row = t >> 7, ch = t & 127;
  bf16x8 w;
  if (ch >= 125){
#pragma unroll
    for (int e=0;e<8;e++) w[e] = 0;
  } else {
    const float* p = dist + (size_t)row*1000 + ch*8;
    f32x4 a = *(const f32x4*)p;
    f32x4 b = *(const f32x4*)(p + 4);
#pragma unroll
    for (int e=0;e<4;e++){ w[e] = (short)f2b(a[e]); w[4+e] = (short)f2b(b[e]); }
  }
  *(bf16x8*)&db[(size_t)row*1024 + ch*8] = w;
}

__global__ void k_embed(const float* __restrict__ data, const float* __restrict__ We,
                        const float* __restrict__ be, float* __restrict__ x,
                        unsigned short* __restrict__ xb){
  int idx = blockIdx.x*256 + threadIdx.x;
  int d = idx & 127, bn = idx >> 7;
  float v = data[bn*2]*We[d*2] + data[bn*2+1]*We[d*2+1] + be[d];
  x[idx] = v; xb[idx] = f2b(v);
}

// ---------------- norm-scale reduce: part -> na,nc [32][128] ----------------
__global__ void k_scale(const float* __restrict__ part, int cnt,
                        const float* __restrict__ g, const float* __restrict__ beta,
                        float* __restrict__ na, float* __restrict__ nc){
  int b = blockIdx.x, d = threadIdx.x;   // 32 x 128
  float s1 = 0.f, s2 = 0.f;
  for (int c = 0; c < cnt; ++c){
    size_t pi = (((size_t)b*cnt + c)*128 + d)*2;
    s1 += part[pi]; s2 += part[pi+1];
  }
  float mean = s1 * 1e-3f;
  float var  = s2 * 1e-3f - mean*mean;
  float a = g[d] * rsqrtf(var + 1e-5f);
  na[b*128 + d] = a; nc[b*128 + d] = beta[d] - mean*a;
}

// ---------------- final apply: dout = x*na+nc ----------------
__global__ __launch_bounds__(256) void k_fapply(
  const float* __restrict__ x, const float* __restrict__ na,
  const float* __restrict__ nc, float* __restrict__ dout){
  int blk = blockIdx.x, tid = threadIdx.x;
  int b = blk / 125;
  size_t base = (size_t)blk*1024 + tid*4;
  int d0 = (tid*4) & 127;
  f32x4 v = *(const f32x4*)&x[base];
  f32x4 o;
#pragma unroll
  for (int e=0;e<4;e++) o[e] = v[e]*na[b*128 + d0 + e] + nc[b*128 + d0 + e];
  *(f32x4*)&dout[base] = o;
}

// ---------------- fused QKV GEMM (+inline norm2 of prev layer) ----------------
// grid (512, 2), x XCD-swizzled: y: 0=Q->sigq, 1=KV->Zc
template<int NORM>
__global__ __launch_bounds__(256) void k_qkv(
  const unsigned short* __restrict__ xb, const float* __restrict__ x,
  const float* __restrict__ na2, const float* __restrict__ nc2,
  const unsigned short* __restrict__ Wqb, const unsigned short* __restrict__ Wkb,
  const unsigned short* __restrict__ Wvb,
  unsigned short* __restrict__ sigq, unsigned short* __restrict__ Zc)
{
  __shared__ unsigned short LA[2*2048];          // [buf][4][64][8]
  __shared__ unsigned short LB[2][4][256][8];
  __shared__ float sna[128], snc[128];
  int tid = threadIdx.x, wid = tid>>6, lane = tid&63;
  int l15 = lane&15, lg = lane>>4;
  int wm = wid>>1, wn = wid&1;
  int b, t; bdecode(blockIdx.x, b, t);
  int kv = blockIdx.y;
  int lrow = t*64 + lane; if (lrow > 999) lrow = 999;
  size_t arow = (size_t)(b*1000 + lrow);

  if (NORM){
    if (tid < 128){ sna[tid] = na2[b*128 + tid]; snc[tid] = nc2[b*128 + tid]; }
    __syncthreads();
  }

  f32x4 zf = {0.f,0.f,0.f,0.f};
  f32x4 acc[2][4], acc2[2][4];
#pragma unroll
  for (int i=0;i<2;i++)
#pragma unroll
    for (int j=0;j<4;j++){ acc[i][j] = zf; acc2[i][j] = zf; }

  auto stage = [&](int kk, int buf){
    int k0 = kk*32;
    if (NORM){
      const float* p = x + arow*128 + k0 + wid*8;
      f32x4 v0 = *(const f32x4*)p;
      f32x4 v1 = *(const f32x4*)(p + 4);
      bf16x8 w;
#pragma unroll
      for (int e=0;e<4;e++){
        int k = k0 + wid*8;
        w[e]   = (short)f2b(v0[e]*sna[k+e]   + snc[k+e]);
        w[4+e] = (short)f2b(v1[e]*sna[k+4+e] + snc[k+4+e]);
      }
      *(bf16x8*)&LA[buf*2048 + wid*512 + lane*8] = w;
    } else {
      gl16(xb + arow*128 + k0 + wid*8, &LA[buf*2048 + wid*512]);
    }
    if (kv == 0){
#pragma unroll
      for (int t2=0;t2<2;++t2){
        int e = wid + t2*4, g2 = e>>1, nb = e&1;
        gl16(Wqb + (size_t)(nb*64+lane)*128 + k0 + g2*8, &LB[buf][g2][nb*64][0]);
      }
    } else {
#pragma unroll
      for (int t2=0;t2<4;++t2){
        int e = wid + t2*4, g2 = e&3, nb = e>>2;
        const unsigned short* src = (nb < 2)
          ? Wkb + (size_t)(nb*64+lane)*128 + k0 + g2*8
          : Wvb + (size_t)((nb-2)*64+lane)*128 + k0 + g2*8;
        gl16(src, &LB[buf][g2][nb*64][0]);
      }
    }
  };
  auto compute = [&](int buf){
    bf16x8 af[2];
#pragma unroll
    for (int i=0;i<2;i++){
      int row = wm*32 + i*16 + l15;
      af[i] = *(const bf16x8*)&LA[buf*2048 + lg*512 + row*8];
    }
#pragma unroll
    for (int j=0;j<4;j++){
      bf16x8 bq = *(const bf16x8*)&LB[buf][lg][wn*64 + j*16 + l15][0];
#pragma unroll
      for (int i=0;i<2;i++) acc[i][j] = mfma16(af[i], bq, acc[i][j]);
      if (kv){
        bf16x8 bv = *(const bf16x8*)&LB[buf][lg][128 + wn*64 + j*16 + l15][0];
#pragma unroll
        for (int i=0;i<2;i++) acc2[i][j] = mfma16(af[i], bv, acc2[i][j]);
      }
    }
  };

  stage(0, 0);
  __syncthreads();
  for (int kk = 0; kk < 4; ++kk){
    int buf = kk & 1;
    if (kk < 3) stage(kk+1, buf^1);
    compute(buf);
    __syncthreads();
  }

#pragma unroll
  for (int i=0;i<2;i++){
    int m4 = t*64 + wm*32 + i*16 + lg*4;
    if (m4 >= 1000) continue;
#pragma unroll
    for (int j=0;j<4;j++){
      int col = wn*64 + j*16 + l15;
      if (kv == 0){
#pragma unroll
        for (int r=0;r<4;r++)
          sigq[(size_t)(b*1000 + m4 + r)*128 + col] = f2b(1.f/(1.f + __expf(-acc[i][j][r])));
      } else {
        s16x4 pv, pk;
#pragma unroll
        for (int r=0;r<4;r++){
          float ek = __expf(acc[i][j][r]);
          pk[r] = (short)f2b(ek);
          pv[r] = (short)f2b(ek * acc2[i][j][r]);
        }
        size_t base = ((size_t)(b*128 + (m4>>3))*256 + col)*8 + ((m4>>2)&1)*4;
        *(s16x4*)&Zc[base] = pv;
        *(s16x4*)&Zc[base + 1024] = pk;
      }
    }
  }
}

// ---------------- fused attention (+inline norm2) + stats ----------------
// grid 512 linear, XCD-swizzled; BK=64, 4 waves, gl16 B-staging, 1 barrier/step
template<int NORM, int USE16>
__global__ __launch_bounds__(256) void k_attn(
  const float* __restrict__ dist, const unsigned short* __restrict__ db16,
  const unsigned short* __restrict__ Zc, const unsigned short* __restrict__ sigq,
  float* __restrict__ x, float* __restrict__ partA,
  const float* __restrict__ na2, const float* __restrict__ nc2,
  const float* __restrict__ log_scale, const float* __restrict__ alpha, int layer)
{
  union SM {
    struct { unsigned short A[2][8][64][8]; unsigned short B[2][8][256][8]; } st;
    float den[64][128];
  };
  __shared__ SM sm;
  int tid = threadIdx.x, wid = tid>>6, lane = tid&63;
  int l15 = lane&15, lg = lane>>4;
  int bb, t; bdecode(blockIdx.x, bb, t);
  int n0 = t*64;
  float sc = log_scale[0]*alpha[layer];
  const unsigned short* Zb = Zc + ((size_t)bb << 18);
  int an = n0 + lane; if (an > 999) an = 999;     // staging row = lane, chunks {wid, wid+4}
  const size_t drow = (size_t)(bb*1000 + an);

  f32x4 zf = {0.f,0.f,0.f,0.f};
  f32x4 acc[4][4];
#pragma unroll
  for (int i=0;i<4;i++)
#pragma unroll
    for (int j=0;j<4;j++) acc[i][j] = zf;

  auto issueB = [&](int kk, int buf){
#pragma unroll
    for (int t2=0;t2<8;++t2){
      int e = wid + t2*4;            // 0..31 wave-uniform
      int g2 = e >> 2, cb = e & 3;   // chunk 0..7, col-block 0..3
      gl16(Zb + ((size_t)((kk*8 + g2)*256 + cb*64 + lane))*8, &sm.st.B[buf][g2][cb*64][0]);
    }
  };
  auto loadA2 = [&](int kk, float* v0, float* v1){
    int k0 = kk*64 + wid*8;
    int k1 = k0 + 32;                // chunk wid+4
    if (USE16){
      bf16x8 r0 = *(const bf16x8*)(db16 + drow*1024 + k0);
      bf16x8 r1 = *(const bf16x8*)(db16 + drow*1024 + k1);
#pragma unroll
      for (int e=0;e<8;e++){ v0[e] = b2f((unsigned short)r0[e]); v1[e] = b2f((unsigned short)r1[e]); }
    } else {
      const float* dp = dist + drow*1000;
#pragma unroll
      for (int e=0;e<8;e++){
        int m0 = k0 + e; if (m0 > 999) m0 = 999;
        int m1 = k1 + e; if (m1 > 999) m1 = 999;
        v0[e] = dp[m0]; v1[e] = dp[m1];
      }
    }
  };
  auto expwrite2 = [&](const float* v0, const float* v1, int buf){
    bf16x8 w0, w1;
#pragma unroll
    for (int e=0;e<8;e++){
      w0[e] = (short)f2b(__expf(sc*v0[e]));
      w1[e] = (short)f2b(__expf(sc*v1[e]));
    }
    *(bf16x8*)&sm.st.A[buf][wid][lane][0]     = w0;   // contiguous 1KB per wave
    *(bf16x8*)&sm.st.A[buf][wid+4][lane][0]   = w1;
  };
  auto compute = [&](int buf){
#pragma unroll
    for (int ks=0; ks<2; ++ks){
      bf16x8 af[4], bq[4];
#pragma unroll
      for (int i=0;i<4;i++) af[i] = *(const bf16x8*)&sm.st.A[buf][ks*4+lg][i*16 + l15][0];
#pragma unroll
      for (int j=0;j<4;j++) bq[j] = *(const bf16x8*)&sm.st.B[buf][ks*4+lg][wid*64 + j*16 + l15][0];
#pragma unroll
      for (int i=0;i<4;i++)
#pragma unroll
        for (int j=0;j<4;j++)
          acc[i][j] = mfma16(af[i], bq[j], acc[i][j]);
    }
  };

  float av0[8], av1[8];
  issueB(0, 0);
  loadA2(0, av0, av1);
  expwrite2(av0, av1, 0);
  __syncthreads();
  for (int kk = 0; kk < 16; ++kk){
    int buf = kk & 1;
    float nv0[8], nv1[8];
    if (kk < 15){ issueB(kk+1, buf^1); loadA2(kk+1, nv0, nv1); }
    compute(buf);
    if (kk < 15) expwrite2(nv0, nv1, buf^1);
    __syncthreads();
  }

  if (wid >= 2){
#pragma unroll
    for (int i=0;i<4;i++)
#pragma unroll
      for (int j=0;j<4;j++){
        int dcol = (wid-2)*64 + j*16 + l15;
#pragma unroll
        for (int r=0;r<4;r++)
          sm.den[i*16 + lg*4 + r][dcol] = acc[i][j][r];
      }
  }
  __syncthreads();
  if (wid < 2){
    float nav[4], ncv[4];
    if (NORM){
#pragma unroll
      for (int j=0;j<4;j++){
        int d = wid*64 + j*16 + l15;
        nav[j] = na2[bb*128 + d]; ncv[j] = nc2[bb*128 + d];
      }
    }
    float s1[4] = {0.f,0.f,0.f,0.f}, s2[4] = {0.f,0.f,0.f,0.f};
#pragma unroll
    for (int i=0;i<4;i++){
#pragma unroll
      for (int r=0;r<4;r++){
        int n = n0 + i*16 + lg*4 + r;
        if (n < 1000){
          size_t rowi = ((size_t)bb*1000 + n)*128;
#pragma unroll
          for (int j=0;j<4;j++){
            int d = wid*64 + j*16 + l15;
            float xv = x[rowi + d];
            if (NORM) xv = xv*nav[j] + ncv[j];
            float y = xv + b2f(sigq[rowi + d]) * acc[i][j][r] / sm.den[i*16 + lg*4 + r][d];
            x[rowi + d] = y;
            s1[j] += y; s2[j] += y*y;
          }
        }
      }
    }
#pragma unroll
    for (int j=0;j<4;j++){
      s1[j] += __shfl_xor(s1[j], 16); s2[j] += __shfl_xor(s2[j], 16);
      s1[j] += __shfl_xor(s1[j], 32); s2[j] += __shfl_xor(s2[j], 32);
    }
    if (lg == 0){
#pragma unroll
      for (int j=0;j<4;j++){
        int d = wid*64 + j*16 + l15;
        size_t pi = (((size_t)bb*16 + t)*128 + d)*2;
        partA[pi] = s1[j]; partA[pi+1] = s2[j];
      }
    }
  }
}

// ---------------- FF1 + fused norm1 ----------------
// grid 512 XCD-swizzled, 512 thr, BN=512, K=128; side out: x1 = inorm1(x) f32
__global__ __launch_bounds__(512) void k_ff1(
  const float* __restrict__ x, const float* __restrict__ partA,
  const float* __restrict__ g1, const float* __restrict__ b1,
  const unsigned short* __restrict__ W1b, const float* __restrict__ bw1,
  float* __restrict__ x1, unsigned short* __restrict__ h1)
{
  __shared__ unsigned short LA[2][4][64][8];
  __shared__ unsigned short LB[2][4][512][8];
  __shared__ float sna[128], snc[128];
  int tid = threadIdx.x, wid = tid>>6, lane = tid&63;
  int l15 = lane&15, lg = lane>>4;
  int wm = wid>>2, wn = wid&3;
  int b, t; bdecode(blockIdx.x, b, t);

  if (tid < 128){
    float s1 = 0.f, s2 = 0.f;
    for (int c = 0; c < 16; ++c){
      size_t pi = (((size_t)b*16 + c)*128 + tid)*2;
      s1 += partA[pi]; s2 += partA[pi+1];
    }
    float mean = s1 * 1e-3f;
    float var  = s2 * 1e-3f - mean*mean;
    float a = g1[tid] * rsqrtf(var + 1e-5f);
    sna[tid] = a; snc[tid] = b1[tid] - mean*a;
  }
  __syncthreads();

  f32x4 zf = {0.f,0.f,0.f,0.f};
  f32x4 acc[2][8];
#pragma unroll
  for (int i=0;i<2;i++)
#pragma unroll
    for (int j=0;j<8;j++) acc[i][j] = zf;

  auto stage = [&](int kk, int buf){
    int k0 = kk*32;
    if (tid < 256){
      int row = tid & 63, g2 = tid >> 6;
      int lr = t*64 + row;
      int rr = lr > 999 ? 999 : lr;
      const float* p = x + ((size_t)(b*1000 + rr))*128 + k0 + g2*8;
      f32x4 v0 = *(const f32x4*)p;
      f32x4 v1 = *(const f32x4*)(p + 4);
      f32x4 o0, o1;
      bf16x8 w;
#pragma unroll
      for (int e=0;e<4;e++){
        int k = k0 + g2*8;
        o0[e] = v0[e]*sna[k+e]   + snc[k+e];
        o1[e] = v1[e]*sna[k+4+e] + snc[k+4+e];
        w[e]   = (short)f2b(o0[e]);
        w[4+e] = (short)f2b(o1[e]);
      }
      *(bf16x8*)&LA[buf][g2][row][0] = w;
      if (lr < 1000){
        float* q = x1 + ((size_t)(b*1000 + lr))*128 + k0 + g2*8;
        *(f32x4*)q = o0; *(f32x4*)(q+4) = o1;
      }
    }
#pragma unroll
    for (int t2=0;t2<4;++t2){
      int e = wid*4 + t2;
      int g2 = e & 3, nb = e >> 2;
      gl16(W1b + (size_t)(nb*64 + lane)*128 + k0 + g2*8, &LB[buf][g2][nb*64][0]);
    }
  };
  auto compute = [&](int buf){
    bf16x8 af[2];
#pragma unroll
    for (int i=0;i<2;i++) af[i] = *(const bf16x8*)&LA[buf][lg][wm*32 + i*16 + l15][0];
#pragma unroll
    for (int j=0;j<8;j++){
      bf16x8 bq = *(const bf16x8*)&LB[buf][lg][wn*128 + j*16 + l15][0];
#pragma unroll
      for (int i=0;i<2;i++) acc[i][j] = mfma16(af[i], bq, acc[i][j]);
    }
  };

  stage(0, 0);
  __syncthreads();
  for (int kk = 0; kk < 4; ++kk){
    int buf = kk & 1;
    if (kk < 3) stage(kk+1, buf^1);
    compute(buf);
    __syncthreads();
  }

#pragma unroll
  for (int i=0;i<2;i++){
    int m4 = t*64 + wm*32 + i*16 + lg*4;
    if (m4 >= 1000) continue;
#pragma unroll
    for (int j=0;j<8;j++){
      int col = wn*128 + j*16 + l15;
      float bz = bw1[col];
#pragma unroll
      for (int r=0;r<4;r++){
        float v = acc[i][j][r] + bz;
        h1[(size_t)(b*1000 + m4 + r)*512 + col] = f2b(v > 0.f ? v : 0.f);
      }
    }
  }
}

// ---------------- FF2 + residual(f32) + stats ----------------
// grid 512 XCD-swizzled, K=512
__global__ __launch_bounds__(256) void k_ff2(
  const unsigned short* __restrict__ h1, const unsigned short* __restrict__ W2b,
  const float* __restrict__ bw2, const float* __restrict__ x1,
  float* __restrict__ x, float* __restrict__ partF)
{
  __shared__ unsigned short LA[2][4][64][8];
  __shared__ unsigned short LB[2][4][128][8];
  int tid = threadIdx.x, wid = tid>>6, lane = tid&63;
  int l15 = lane&15, lg = lane>>4;
  int wm = wid>>1, wn = wid&1;
  int b, t; bdecode(blockIdx.x, b, t);
  int lrow = t*64 + lane; if (lrow > 999) lrow = 999;
  size_t arow = (size_t)(b*1000 + lrow);

  f32x4 zf = {0.f,0.f,0.f,0.f};
  f32x4 acc[2][4];
#pragma unroll
  for (int i=0;i<2;i++)
#pragma unroll
    for (int j=0;j<4;j++) acc[i][j] = zf;

  auto stage = [&](int kk, int buf){
    int k0 = kk*32;
    gl16(h1 + arow*512 + k0 + wid*8, &LA[buf][wid][0][0]);
#pragma unroll
    for (int t2=0;t2<2;++t2){
      int e = wid + t2*4, g2 = e>>1, nb = e&1;
      gl16(W2b + (size_t)(nb*64 + lane)*512 + k0 + g2*8, &LB[buf][g2][nb*64][0]);
    }
  };
  auto compute = [&](int buf){
    bf16x8 af[2];
#pragma unroll
    for (int i=0;i<2;i++) af[i] = *(const bf16x8*)&LA[buf][lg][wm*32 + i*16 + l15][0];
#pragma unroll
    for (int j=0;j<4;j++){
      bf16x8 bq = *(const bf16x8*)&LB[buf][lg][wn*64 + j*16 + l15][0];
#pragma unroll
      for (int i=0;i<2;i++) acc[i][j] = mfma16(af[i], bq, acc[i][j]);
    }
  };

  stage(0, 0);
  __syncthreads();
  for (int kk = 0; kk < 16; ++kk){
    int buf = kk & 1;
    if (kk < 15) stage(kk+1, buf^1);
    compute(buf);
    __syncthreads();
  }

  float s1[4] = {0.f,0.f,0.f,0.f}, s2[4] = {0.f,0.f,0.f,0.f};
#pragma unroll
  for (int i=0;i<2;i++){
    int m4 = t*64 + wm*32 + i*16 + lg*4;
    if (m4 >= 1000) continue;
#pragma unroll
    for (int j=0;j<4;j++){
      int col = wn*64 + j*16 + l15;
      float bz = bw2[col];
#pragma unroll
      for (int r=0;r<4;r++){
        size_t idx = (size_t)(b*1000 + m4 + r)*128 + col;
        float y = acc[i][j][r] + bz + x1[idx];
        x[idx] = y;
        s1[j] += y; s2[j] += y*y;
      }
    }
  }
#pragma unroll
  for (int j=0;j<4;j++){
    s1[j] += __shfl_xor(s1[j], 16); s2[j] += __shfl_xor(s2[j], 16);
    s1[j] += __shfl_xor(s1[j], 32); s2[j] += __shfl_xor(s2[j], 32);
  }
  if (lg == 0){
#pragma unroll
    for (int j=0;j<4;j++){
      int d = wn*64 + j*16 + l15;
      size_t pi = (((size_t)b*32 + t*2 + wm)*128 + d)*2;
      partF[pi] = s1[j]; partF[pi+1] = s2[j];
    }
  }
}

extern "C" void kernel_launch(void* const* d_in, const int* in_sizes, int n_in,
                              void* d_out, int out_size, void* d_ws, size_t ws_size,
                              hipStream_t stream) {
  const float* data = (const float*)d_in[0];
  const float* dist = (const float*)d_in[1];
  const float* log_scale = (const float*)d_in[2];
  const float* We = (const float*)d_in[3];
  const float* be = (const float*)d_in[4];
  const float* Wq = (const float*)d_in[5];
  const float* Wk = (const float*)d_in[6];
  const float* Wv = (const float*)d_in[7];
  const float* g1 = (const float*)d_in[8];
  const float* b1 = (const float*)d_in[9];
  const float* W1 = (const float*)d_in[10];
  const float* bw1 = (const float*)d_in[11];
  const float* W2 = (const float*)d_in[12];
  const float* bw2 = (const float*)d_in[13];
  const float* g2 = (const float*)d_in[14];
  const float* b2 = (const float*)d_in[15];
  const float* alpha = (const float*)d_in[16];
  float* dout = (float*)d_out;

  char* ws = (char*)d_ws;
  size_t off = 0;
  auto alloc = [&](size_t bytes) -> void* {
    void* p = ws + off; off += (bytes + 255) & ~(size_t)255; return p;
  };
  unsigned short* xb  = (unsigned short*)alloc(8192000);    // [32000][128] bf16
  float* x            = (float*)alloc(16384000);            // [32000][128] f32
  unsigned short* sigq= (unsigned short*)alloc(8192000);    // [32000][128] bf16
  unsigned short* Zc  = (unsigned short*)alloc(16777216);   // [32][128][256][8] bf16
  unsigned short* h1  = (unsigned short*)alloc(32768000);   // [32000][512] bf16
  float* x1           = (float*)alloc(16384000);            // [32000][128] f32
  float* partA        = (float*)alloc(524288);              // [32][16][128][2]
  float* partF        = (float*)alloc(1048576);             // [32][32][128][2]
  float* na2          = (float*)alloc(16384);
  float* nc2          = (float*)alloc(16384);
  unsigned short* wqb = (unsigned short*)alloc(196608);
  unsigned short* wkb = (unsigned short*)alloc(196608);
  unsigned short* wvb = (unsigned short*)alloc(196608);
  unsigned short* w1b = (unsigned short*)alloc(786432);
  unsigned short* w2b = (unsigned short*)alloc(786432);
  if (off > ws_size) return;
  unsigned short* db16p = nullptr;
  if (ws_size >= off + 131072256) db16p = (unsigned short*)alloc(131072000); // [32000][1024] bf16

  hipMemsetAsync(Zc, 0, 16777216, stream);
  k_cvt5<<<4224, 256, 0, stream>>>(Wq, Wk, Wv, W1, W2, wqb, wkb, wvb, w1b, w2b);
  if (db16p) k_cvtdist<<<16000, 256, 0, stream>>>(dist, db16p);
  k_embed<<<16000, 256, 0, stream>>>(data, We, be, x, xb);

  for (int i = 0; i < LCOUNT; ++i){
    if (i > 0)
      k_scale<<<32, 128, 0, stream>>>(partF, 32, g2 + (i-1)*128, b2 + (i-1)*128, na2, nc2);
    if (i == 0)
      k_qkv<0><<<dim3(512,2), 256, 0, stream>>>(xb, x, nullptr, nullptr,
                                                wqb + i*16384, wkb + i*16384, wvb + i*16384,
                                                sigq, Zc);
    else
      k_qkv<1><<<dim3(512,2), 256, 0, stream>>>(nullptr, x, na2, nc2,
                                                wqb + i*16384, wkb + i*16384, wvb + i*16384,
                                                sigq, Zc);
    if (i == 0){
      if (db16p) k_attn<0,1><<<512, 256, 0, stream>>>(dist, db16p, Zc, sigq, x, partA,
                                                      nullptr, nullptr, log_scale, alpha, i);
      else       k_attn<0,0><<<512, 256, 0, stream>>>(dist, nullptr, Zc, sigq, x, partA,
                                                      nullptr, nullptr, log_scale, alpha, i);
    } else {
      if (db16p) k_attn<1,1><<<512, 256, 0, stream>>>(dist, db16p, Zc, sigq, x, partA,
                                                      na2, nc2, log_scale, alpha, i);
      else       k_attn<1,0><<<512, 256, 0, stream>>>(dist, nullptr, Zc, sigq, x, partA,
                                                      na2, nc2, log_scale, alpha, i);
    }
    k_ff1<<<512, 512, 0, stream>>>(x, partA, g1 + i*128, b1 + i*128,
                                   w1b + i*65536, bw1 + i*512, x1, h1);
    k_ff2<<<512, 256, 0, stream>>>(h1, w2b + i*65536, bw2 + i*128, x1, x, partF);
  }
  k_scale<<<32, 128, 0, stream>>>(partF, 32, g2 + 5*128, b2 + 5*128, na2, nc2);
  k_fapply<<<4000, 256, 0, stream>>>(x, na2, nc2, dout);
}